// Round 3
// baseline (1108.880 us; speedup 1.0000x reference)
//
#include <hip/hip_runtime.h>
#include <math.h>

// Problem constants
#define Bq 1024
#define Dd 512
#define Nn 131072
#define Kk 16
#define Mm 32    // candidates rescored in f64 per row
#define CPR 8192 // candidates per row: 1024 col-blocks x 2 halves x top-4

// Output layout (flat concat, reference return order)
#define OUT_SC  0
#define OUT_IDX (Bq * Kk)
#define OUT_SEQ (2 * Bq * Kk)
#define OUT_LAB (2 * Bq * Kk + Bq * Kk * Dd)

using bf16x8 = __attribute__((ext_vector_type(8))) __bf16;
using f32x4  = __attribute__((ext_vector_type(4))) float;

__device__ __forceinline__ unsigned short f2bf(float f) {  // RNE f32->bf16
  unsigned u = __builtin_bit_cast(unsigned, f);
  return (unsigned short)((u + 0x7FFFu + ((u >> 16) & 1u)) >> 16);
}
__device__ __forceinline__ float bf2f(unsigned short b) {
  return __builtin_bit_cast(float, (unsigned)b << 16);
}
// monotone 16-bit key for bf16 pattern (u32 compare == float compare)
__device__ __forceinline__ unsigned key16(unsigned short b) {
  return (unsigned)(unsigned short)(b ^ ((b & 0x8000u) ? 0xFFFFu : 0x8000u));
}
__device__ __forceinline__ float unkey16(unsigned k) {
  const unsigned short b =
      (unsigned short)((k & 0x8000u) ? (k ^ 0x8000u) : (k ^ 0xFFFFu));
  return bf2f(b);
}

// async global->LDS, 16B per lane (dst must be wave-uniform base + lane*16)
#define GLD16(gp, lp)                                                   \
  __builtin_amdgcn_global_load_lds(                                     \
      (const __attribute__((address_space(1))) unsigned int*)(gp),      \
      (__attribute__((address_space(3))) unsigned int*)(lp), 16, 0, 0)

// ---------------------------------------------------------------------------
// Kernel 1: L2-normalize queries -> bf16, pre-swizzled for LDS A-tile.
// ---------------------------------------------------------------------------
__global__ __launch_bounds__(256) void k_norm(const float* __restrict__ q,
                                              unsigned short* __restrict__ qb) {
  const int row = blockIdx.x;
  const int t = threadIdx.x;
  const float v0 = q[row * Dd + t];
  const float v1 = q[row * Dd + t + 256];
  float ss = v0 * v0 + v1 * v1;
#pragma unroll
  for (int m = 32; m >= 1; m >>= 1) ss += __shfl_xor(ss, m);
  __shared__ float wsum[4];
  if ((t & 63) == 0) wsum[t >> 6] = ss;
  __syncthreads();
  const float inv = rsqrtf(wsum[0] + wsum[1] + wsum[2] + wsum[3]);
  const int r7 = row & 7;
  const int k0 = t;
  const int p0 = (k0 & ~0x38) | ((((k0 >> 3) & 7) ^ r7) << 3);
  qb[row * Dd + p0] = f2bf(v0 * inv);
  const int k1 = t + 256;
  const int p1 = (k1 & ~0x38) | ((((k1 >> 3) & 7) ^ r7) << 3);
  qb[row * Dd + p1] = f2bf(v1 * inv);
}

// ---------------------------------------------------------------------------
// Kernel 2: bf16 MFMA GEMM with FUSED per-(row, 64-col-half) top-4 selection.
// Block = 256 rows x 128 cols, 4 waves. XCD-locality swizzle: the 4 row-
// sibling blocks of one col-panel get consecutive same-XCD dispatch slots
// (id%8 ~ XCD) so the shared B-panel is an L2 hit instead of 4 HBM fetches.
// Epilogue: scores packed as (key16(bf16)<<16 | col7) -> u32 max-butterfly
// over 16 lanes, 4 extraction rounds -> candq[row][nb*8 + colg*4 + j].
// No sims tensor, no k_select.
// ---------------------------------------------------------------------------
__global__ __launch_bounds__(256, 2) void k_gemm(
    const unsigned short* __restrict__ qb, const float* __restrict__ w,
    unsigned* __restrict__ candq) {
  __shared__ __align__(16) unsigned short As[256 * 64];  // 32 KB
  __shared__ __align__(16) unsigned short Bs[128 * 72];  // 18 KB (pad+swz)
  const int t = threadIdx.x;
  const int l = t & 63;
  const int wv = t >> 6;
  const int m = l & 15;
  const int g = l >> 4;
  const int rowg = wv >> 1;
  const int colg = wv & 1;
  // swizzle: id = 8*j + c ; bx = (j&3), nb = c*128 + (j>>2)
  const unsigned id = blockIdx.x;
  const int bx = (int)((id >> 3) & 3);
  const int nb = (int)((id & 7) * 128 + (id >> 5));
  const int rb = bx * 256;
  const int n0 = nb * 128;
  const int ct = t & 31, dt = t >> 5;

  f32x4 acc[8][4] = {};

  for (int kt = 0; kt < 8; kt++) {
    __syncthreads();
    // stage A: 2048 x 16B chunks via global_load_lds (qb pre-swizzled)
#pragma unroll
    for (int p = 0; p < 8; p++) {
      const int i = p * 256 + t;
      const int r = i >> 3, c = i & 7;
      GLD16(qb + (size_t)(rb + r) * Dd + kt * 64 + c * 8, &As[i * 8]);
    }
    // stage B: 64k x 128n fp32 -> bf16, k-major per col, XOR-swizzled
    {
      const float* src = w + (size_t)(kt * 64 + dt * 8) * Nn + n0 + ct * 4;
#pragma unroll
      for (int h = 0; h < 2; h++) {
        f32x4 f0 = *(const f32x4*)(src + (size_t)(h * 4 + 0) * Nn);
        f32x4 f1 = *(const f32x4*)(src + (size_t)(h * 4 + 1) * Nn);
        f32x4 f2 = *(const f32x4*)(src + (size_t)(h * 4 + 2) * Nn);
        f32x4 f3 = *(const f32x4*)(src + (size_t)(h * 4 + 3) * Nn);
#pragma unroll
        for (int j = 0; j < 4; j++) {
          const int col = ct * 4 + j;
          unsigned* dst =
              (unsigned*)&Bs[col * 72 + ((dt * 8) ^ ((ct & 7) << 3))];
          dst[h * 2 + 0] =
              (unsigned)f2bf(f0[j]) | ((unsigned)f2bf(f1[j]) << 16);
          dst[h * 2 + 1] =
              (unsigned)f2bf(f2[j]) | ((unsigned)f2bf(f3[j]) << 16);
        }
      }
    }
    __syncthreads();
#pragma unroll
    for (int ks = 0; ks < 2; ks++) {
      bf16x8 b[4];
#pragma unroll
      for (int cf = 0; cf < 4; cf++) {
        const int col = colg * 64 + cf * 16 + m;
        const int kpos = (ks * 32 + g * 8) ^ (((col >> 2) & 7) << 3);
        b[cf] = *(const bf16x8*)&Bs[col * 72 + kpos];
      }
#pragma unroll
      for (int rf = 0; rf < 8; rf++) {
        const int row = rowg * 128 + rf * 16 + m;
        const int cc = (ks * 4 + g) ^ (row & 7);
        const bf16x8 a = *(const bf16x8*)&As[row * 64 + cc * 8];
#pragma unroll
        for (int cf = 0; cf < 4; cf++)
          acc[rf][cf] = __builtin_amdgcn_mfma_f32_16x16x32_bf16(
              a, b[cf], acc[rf][cf], 0, 0, 0);
      }
    }
  }

  // epilogue: per row (32 per thread), top-4 of the 64-col half via packed
  // u32 max-butterfly across the 16-lane group. Keys unique per (m,cf) ->
  // unique winner; eliminated slots set to 0 (< any real key).
#pragma unroll
  for (int rf = 0; rf < 8; rf++) {
#pragma unroll
    for (int r = 0; r < 4; r++) {
      const int row = rb + rowg * 128 + rf * 16 + g * 4 + r;
      unsigned k0 = (key16(f2bf(acc[rf][0][r])) << 16) |
                    (unsigned)(colg * 64 + 0 * 16 + m);
      unsigned k1 = (key16(f2bf(acc[rf][1][r])) << 16) |
                    (unsigned)(colg * 64 + 1 * 16 + m);
      unsigned k2 = (key16(f2bf(acc[rf][2][r])) << 16) |
                    (unsigned)(colg * 64 + 2 * 16 + m);
      unsigned k3 = (key16(f2bf(acc[rf][3][r])) << 16) |
                    (unsigned)(colg * 64 + 3 * 16 + m);
      unsigned keep = 0;
#pragma unroll
      for (int round = 0; round < 4; round++) {
        unsigned wvv = k0;
        if (k1 > wvv) wvv = k1;
        if (k2 > wvv) wvv = k2;
        if (k3 > wvv) wvv = k3;
#pragma unroll
        for (int mask = 8; mask >= 1; mask >>= 1) {
          const unsigned o = (unsigned)__shfl_xor((int)wvv, mask);
          if (o > wvv) wvv = o;
        }
        if (k0 == wvv) k0 = 0;
        if (k1 == wvv) k1 = 0;
        if (k2 == wvv) k2 = 0;
        if (k3 == wvv) k3 = 0;
        if (m == round) keep = wvv;
      }
      if (m < 4)
        candq[(size_t)row * CPR + nb * 8 + colg * 4 + m] = keep;
    }
  }
}

// ---------------------------------------------------------------------------
// Kernel 3: tiled transpose w [D][N] fp32 -> wT [N][D] fp32. 128x128 tiles
// (512-B segments both sides), pad 129 on LDS.
// ---------------------------------------------------------------------------
__global__ __launch_bounds__(256) void k_transpose(const float* __restrict__ w,
                                                   float* __restrict__ wT) {
  __shared__ float tile[128][129];  // 66 KB
  const int t = threadIdx.x;
  const int nbase = blockIdx.x * 128;
  const int dbase = blockIdx.y * 128;
  const int c4 = (t & 31) * 4;
  const int rr = t >> 5;  // 0..7
#pragma unroll
  for (int p = 0; p < 16; p++) {
    const int d = p * 8 + rr;
    const f32x4 v = *(const f32x4*)&w[(size_t)(dbase + d) * Nn + nbase + c4];
    tile[c4 + 0][d] = v[0];
    tile[c4 + 1][d] = v[1];
    tile[c4 + 2][d] = v[2];
    tile[c4 + 3][d] = v[3];
  }
  __syncthreads();
#pragma unroll
  for (int p = 0; p < 16; p++) {
    const int n = p * 8 + rr;
    const f32x4 v = {tile[n][c4], tile[n][c4 + 1], tile[n][c4 + 2],
                     tile[n][c4 + 3]};
    *(f32x4*)&wT[(size_t)(nbase + n) * Dd + dbase + c4] = v;
  }
}

// ---------------------------------------------------------------------------
// Kernel 4: per row — wave 0 extracts top-32 from packed candq (u32 compare =
// score desc); f64 rescore (TR: coalesced wT rows); sorted top-16; gather.
// ---------------------------------------------------------------------------
template <bool TR>
__global__ __launch_bounds__(256) void k_final(
    const unsigned* __restrict__ candq, const float* __restrict__ label,
    const float* __restrict__ w, const float* __restrict__ wT,
    const float* __restrict__ q, float* __restrict__ out) {
  const int row = blockIdx.x;
  const int t = threadIdx.x;
  const int lane = t & 63;
  const int wv = t >> 6;

  __shared__ unsigned shp[CPR];  // 32 KB
  __shared__ int sel[Mm];
  __shared__ double resc[Mm];
  __shared__ int sel16[Kk];

#pragma unroll
  for (int j = 0; j < CPR / 256; j++) {
    const int c = j * 256 + t;
    shp[c] = candq[(size_t)row * CPR + c];
  }
  __syncthreads();

  // ---- stage 1: wave 0 extracts top-32 (packed u32 order) ----
  if (t < 64) {
    const int seg = t * (CPR / 64);  // 128 candidates per lane
    unsigned bv = 0;
    int bcol = 0x7fffffff;
    int bp = seg;
    for (int p = seg; p < seg + CPR / 64; p++) {
      const unsigned v = shp[p];
      const int col = ((p >> 3) << 7) | (int)(v & 127u);
      if (v > bv || (v == bv && col < bcol)) { bv = v; bcol = col; bp = p; }
    }
#pragma unroll 1
    for (int it = 0; it < Mm; it++) {
      unsigned s = bv;
      int si = bcol;
      int sl = t;
#pragma unroll
      for (int mk = 32; mk >= 1; mk >>= 1) {
        const unsigned so = (unsigned)__shfl_xor((int)s, mk);
        const int io = __shfl_xor(si, mk);
        const int lo = __shfl_xor(sl, mk);
        if (so > s || (so == s && (io < si || (io == si && lo < sl)))) {
          s = so; si = io; sl = lo;
        }
      }
      if (t == 0) sel[it] = si & (Nn - 1);
      if (t == sl) {
        shp[bp] = 0;
        bv = 0;
        bcol = 0x7fffffff;
        bp = seg;
        for (int p = seg; p < seg + CPR / 64; p++) {
          const unsigned v = shp[p];
          const int col = ((p >> 3) << 7) | (int)(v & 127u);
          if (v > bv || (v == bv && col < bcol)) { bv = v; bcol = col; bp = p; }
        }
      }
    }
  }
  __syncthreads();

  // ---- stage 2: per-lane f64 q-slice + per-wave redundant norm ----
  double qd[8];
#pragma unroll
  for (int j = 0; j < 8; j++) qd[j] = (double)q[row * Dd + lane * 8 + j];
  double nn = 0.0;
#pragma unroll
  for (int j = 0; j < 8; j++) nn += qd[j] * qd[j];
#pragma unroll
  for (int mk = 32; mk >= 1; mk >>= 1) nn += __shfl_xor(nn, mk);
  const double nrm = sqrt(nn);

  // ---- stage 3: wave wv rescores 8 candidates in f64 ----
#pragma unroll 1
  for (int i = 0; i < Mm / 4; i++) {
    const int c = wv * (Mm / 4) + i;
    const int idx = sel[c];
    double d = 0.0;
    if (TR) {
      const float* wr = wT + (size_t)idx * Dd + lane * 8;
      const f32x4 wa = *(const f32x4*)wr;
      const f32x4 wb = *(const f32x4*)(wr + 4);
#pragma unroll
      for (int j = 0; j < 4; j++) d += qd[j] * (double)wa[j];
#pragma unroll
      for (int j = 0; j < 4; j++) d += qd[4 + j] * (double)wb[j];
    } else {
#pragma unroll
      for (int j = 0; j < 8; j++)
        d += qd[j] * (double)w[(size_t)(lane * 8 + j) * Nn + idx];
    }
#pragma unroll
    for (int mk = 32; mk >= 1; mk >>= 1) d += __shfl_xor(d, mk);
    if (lane == 0) resc[c] = d / nrm;
  }
  __syncthreads();

  // ---- stage 4: wave 0: sorted top-16 of 32 f64 scores ----
  float* out_sc = out + OUT_SC;
  float* out_ix = out + OUT_IDX;
  float* out_sq = out + OUT_SEQ;
  float* out_lb = out + OUT_LAB;
  if (t < 64) {
    double s = (t < Mm) ? resc[t] : -INFINITY;
    int ix = (t < Mm) ? sel[t] : 0x7fffffff;
#pragma unroll 1
    for (int it = 0; it < Kk; it++) {
      double bs2 = s;
      int bi2 = ix;
      int bl = t;
#pragma unroll
      for (int mk = 32; mk >= 1; mk >>= 1) {
        const double so = __shfl_xor(bs2, mk);
        const int io = __shfl_xor(bi2, mk);
        const int lo = __shfl_xor(bl, mk);
        if (so > bs2 || (so == bs2 && (io < bi2 || (io == bi2 && lo < bl)))) {
          bs2 = so; bi2 = io; bl = lo;
        }
      }
      if (t == 0) {
        const int safe = bi2 & (Nn - 1);
        out_sc[row * Kk + it] = (float)bs2;
        out_ix[row * Kk + it] = (float)bi2;
        out_lb[row * Kk + it] = label[safe];
        sel16[it] = safe;
      }
      if (t == bl) { s = -INFINITY; ix = 0x7fffffff; }
    }
  }
  __syncthreads();

  // ---- stage 5: gather the 16 winning weight columns ----
#pragma unroll 1
  for (int j = 0; j < Kk; j++) {
    const int idx = sel16[j];
    if (TR) {
      out_sq[(size_t)(row * Kk + j) * Dd + t] = wT[(size_t)idx * Dd + t];
      out_sq[(size_t)(row * Kk + j) * Dd + t + 256] =
          wT[(size_t)idx * Dd + t + 256];
    } else {
      out_sq[(size_t)(row * Kk + j) * Dd + t] = w[(size_t)t * Nn + idx];
      out_sq[(size_t)(row * Kk + j) * Dd + t + 256] =
          w[(size_t)(t + 256) * Nn + idx];
    }
  }
}

// ---------------------------------------------------------------------------
extern "C" void kernel_launch(void* const* d_in, const int* in_sizes, int n_in,
                              void* d_out, int out_size, void* d_ws,
                              size_t ws_size, hipStream_t stream) {
  const float* q = (const float*)d_in[0];
  const float* w = (const float*)d_in[1];
  const float* lab = (const float*)d_in[2];
  float* out = (float*)d_out;

  // workspace: qb bf16 swz (1 MB) | candq u32 (32 MB) | wT fp32 (268 MB)
  unsigned short* qb = (unsigned short*)d_ws;
  unsigned* candq = (unsigned*)((char*)d_ws + (size_t)Bq * Dd * 2);
  float* wT = (float*)((char*)candq + (size_t)Bq * CPR * 4);

  const size_t need =
      (size_t)Bq * Dd * 2 + (size_t)Bq * CPR * 4 + (size_t)Nn * Dd * 4;

  k_norm<<<Bq, 256, 0, stream>>>(q, qb);
  k_gemm<<<4096, 256, 0, stream>>>(qb, w, candq);
  if (ws_size >= need) {
    k_transpose<<<dim3(Nn / 128, Dd / 128), 256, 0, stream>>>(w, wT);
    k_final<true><<<Bq, 256, 0, stream>>>(candq, lab, w, wT, q, out);
  } else {
    k_final<false><<<Bq, 256, 0, stream>>>(candq, lab, w, wT, q, out);
  }
}

// Round 4
// 680.153 us; speedup vs baseline: 1.6303x; 1.6303x over previous
//
#include <hip/hip_runtime.h>
#include <math.h>

// Problem constants
#define Bq 1024
#define Dd 512
#define Nn 131072
#define Kk 16
#define Mm 32    // candidates rescored in f64 per row
#define CPR 4096 // candidates per row: 1024 col-blocks x top-4

// Output layout (flat concat, reference return order)
#define OUT_SC  0
#define OUT_IDX (Bq * Kk)
#define OUT_SEQ (2 * Bq * Kk)
#define OUT_LAB (2 * Bq * Kk + Bq * Kk * Dd)

using bf16x8 = __attribute__((ext_vector_type(8))) __bf16;
using f32x4  = __attribute__((ext_vector_type(4))) float;
using u16x8  = __attribute__((ext_vector_type(8))) unsigned short;
using u32x4  = __attribute__((ext_vector_type(4))) unsigned;

__device__ __forceinline__ unsigned short f2bf(float f) {  // RNE f32->bf16
  unsigned u = __builtin_bit_cast(unsigned, f);
  return (unsigned short)((u + 0x7FFFu + ((u >> 16) & 1u)) >> 16);
}
__device__ __forceinline__ float bf2f(unsigned short b) {
  return __builtin_bit_cast(float, (unsigned)b << 16);
}
// monotone 16-bit key for bf16 pattern (u32 compare == float compare)
__device__ __forceinline__ unsigned key16(unsigned short b) {
  return (unsigned)(unsigned short)(b ^ ((b & 0x8000u) ? 0xFFFFu : 0x8000u));
}
// sorted-desc top-4 insertion (x = packed key<<16|col)
__device__ __forceinline__ void ins4(unsigned& s0, unsigned& s1, unsigned& s2,
                                     unsigned& s3, unsigned x) {
  unsigned mx, mn;
  mx = s0 > x ? s0 : x; mn = s0 > x ? x : s0; s0 = mx; x = mn;
  mx = s1 > x ? s1 : x; mn = s1 > x ? x : s1; s1 = mx; x = mn;
  mx = s2 > x ? s2 : x; mn = s2 > x ? x : s2; s2 = mx; x = mn;
  s3 = s3 > x ? s3 : x;
}

// async global->LDS, 16B per lane (dst must be wave-uniform base + lane*16)
#define GLD16(gp, lp)                                                   \
  __builtin_amdgcn_global_load_lds(                                     \
      (const __attribute__((address_space(1))) unsigned int*)(gp),      \
      (__attribute__((address_space(3))) unsigned int*)(lp), 16, 0, 0)

// ---------------------------------------------------------------------------
// Kernel 1: L2-normalize queries -> bf16, pre-swizzled for LDS A-tile.
// ---------------------------------------------------------------------------
__global__ __launch_bounds__(256) void k_norm(const float* __restrict__ q,
                                              unsigned short* __restrict__ qb) {
  const int row = blockIdx.x;
  const int t = threadIdx.x;
  const float v0 = q[row * Dd + t];
  const float v1 = q[row * Dd + t + 256];
  float ss = v0 * v0 + v1 * v1;
#pragma unroll
  for (int m = 32; m >= 1; m >>= 1) ss += __shfl_xor(ss, m);
  __shared__ float wsum[4];
  if ((t & 63) == 0) wsum[t >> 6] = ss;
  __syncthreads();
  const float inv = rsqrtf(wsum[0] + wsum[1] + wsum[2] + wsum[3]);
  const int r7 = row & 7;
  const int k0 = t;
  const int p0 = (k0 & ~0x38) | ((((k0 >> 3) & 7) ^ r7) << 3);
  qb[row * Dd + p0] = f2bf(v0 * inv);
  const int k1 = t + 256;
  const int p1 = (k1 & ~0x38) | ((((k1 >> 3) & 7) ^ r7) << 3);
  qb[row * Dd + p1] = f2bf(v1 * inv);
}

// ---------------------------------------------------------------------------
// Kernel 2: bf16 MFMA GEMM + LDS-staged per-(row,128-col) top-4 selection.
// Main loop identical to R2/R3 (incl. XCD-locality swizzle: FETCH 533->144MB).
// Epilogue: acc -> u16 keys in LDS tile [128][136] (reusing As/Bs space),
// then 2 threads/row scan 64 cols each with guarded insertion top-4, pair-
// merge via 4 shfl -> candq[row][nb*4+j] packed (key16<<16 | col7).
// ---------------------------------------------------------------------------
__global__ __launch_bounds__(256, 2) void k_gemm(
    const unsigned short* __restrict__ qb, const float* __restrict__ w,
    unsigned* __restrict__ candq) {
  __shared__ __align__(16) unsigned char smem[256 * 64 * 2 + 128 * 72 * 2];
  unsigned short* As = (unsigned short*)smem;        // [256*64]
  unsigned short* Bs = As + 256 * 64;                // [128*72]
  const int t = threadIdx.x;
  const int l = t & 63;
  const int wv = t >> 6;
  const int m = l & 15;
  const int g = l >> 4;
  const int rowg = wv >> 1;
  const int colg = wv & 1;
  // swizzle: id = 8*j + c ; bx = (j&3), nb = c*128 + (j>>2)
  const unsigned id = blockIdx.x;
  const int bx = (int)((id >> 3) & 3);
  const int nb = (int)((id & 7) * 128 + (id >> 5));
  const int rb = bx * 256;
  const int n0 = nb * 128;
  const int ct = t & 31, dt = t >> 5;

  f32x4 acc[8][4] = {};

  for (int kt = 0; kt < 8; kt++) {
    __syncthreads();
    // stage A: 2048 x 16B chunks via global_load_lds (qb pre-swizzled)
#pragma unroll
    for (int p = 0; p < 8; p++) {
      const int i = p * 256 + t;
      const int r = i >> 3, c = i & 7;
      GLD16(qb + (size_t)(rb + r) * Dd + kt * 64 + c * 8, &As[i * 8]);
    }
    // stage B: 64k x 128n fp32 -> bf16, k-major per col, XOR-swizzled
    {
      const float* src = w + (size_t)(kt * 64 + dt * 8) * Nn + n0 + ct * 4;
#pragma unroll
      for (int h = 0; h < 2; h++) {
        f32x4 f0 = *(const f32x4*)(src + (size_t)(h * 4 + 0) * Nn);
        f32x4 f1 = *(const f32x4*)(src + (size_t)(h * 4 + 1) * Nn);
        f32x4 f2 = *(const f32x4*)(src + (size_t)(h * 4 + 2) * Nn);
        f32x4 f3 = *(const f32x4*)(src + (size_t)(h * 4 + 3) * Nn);
#pragma unroll
        for (int j = 0; j < 4; j++) {
          const int col = ct * 4 + j;
          unsigned* dst =
              (unsigned*)&Bs[col * 72 + ((dt * 8) ^ ((ct & 7) << 3))];
          dst[h * 2 + 0] =
              (unsigned)f2bf(f0[j]) | ((unsigned)f2bf(f1[j]) << 16);
          dst[h * 2 + 1] =
              (unsigned)f2bf(f2[j]) | ((unsigned)f2bf(f3[j]) << 16);
        }
      }
    }
    __syncthreads();
#pragma unroll
    for (int ks = 0; ks < 2; ks++) {
      bf16x8 b[4];
#pragma unroll
      for (int cf = 0; cf < 4; cf++) {
        const int col = colg * 64 + cf * 16 + m;
        const int kpos = (ks * 32 + g * 8) ^ (((col >> 2) & 7) << 3);
        b[cf] = *(const bf16x8*)&Bs[col * 72 + kpos];
      }
#pragma unroll
      for (int rf = 0; rf < 8; rf++) {
        const int row = rowg * 128 + rf * 16 + m;
        const int cc = (ks * 4 + g) ^ (row & 7);
        const bf16x8 a = *(const bf16x8*)&As[row * 64 + cc * 8];
#pragma unroll
        for (int cf = 0; cf < 4; cf++)
          acc[rf][cf] = __builtin_amdgcn_mfma_f32_16x16x32_bf16(
              a, b[cf], acc[rf][cf], 0, 0, 0);
      }
    }
  }

  // ---- fused selection epilogue ----
  unsigned short* tile = (unsigned short*)smem;  // [128][136] u16 keys
  const int row_h = t >> 1;
  const int ch = t & 1;
#pragma unroll 1
  for (int h = 0; h < 2; h++) {
    __syncthreads();  // protect As/Bs (h=0) or prev tile reads (h=1)
    if (rowg == h) {
#pragma unroll
      for (int rf = 0; rf < 8; rf++)
#pragma unroll
        for (int r = 0; r < 4; r++) {
          const int rr = rf * 16 + g * 4 + r;
#pragma unroll
          for (int cf = 0; cf < 4; cf++)
            tile[rr * 136 + colg * 64 + cf * 16 + m] =
                (unsigned short)key16(f2bf(acc[rf][cf][r]));
        }
    }
    __syncthreads();
    // scan my 64-col half of row row_h: guarded insertion top-4
    unsigned s0 = 0, s1 = 0, s2 = 0, s3 = 0;
    const unsigned short* trow = &tile[row_h * 136 + ch * 64];
#pragma unroll
    for (int i = 0; i < 8; i++) {
      const u16x8 tv = *(const u16x8*)&trow[i * 8];
      unsigned mx = tv[0];
#pragma unroll
      for (int j = 1; j < 8; j++) {
        const unsigned k = tv[j];
        if (k > mx) mx = k;
      }
      if (mx > (s3 >> 16)) {
#pragma unroll
        for (int j = 0; j < 8; j++) {
          const unsigned k = tv[j];
          if (k > (s3 >> 16))
            ins4(s0, s1, s2, s3,
                 (k << 16) | (unsigned)(ch * 64 + i * 8 + j));
        }
      }
    }
    // merge partner half (lane t^1, same wave)
    const unsigned p0 = (unsigned)__shfl_xor((int)s0, 1);
    const unsigned p1 = (unsigned)__shfl_xor((int)s1, 1);
    const unsigned p2 = (unsigned)__shfl_xor((int)s2, 1);
    const unsigned p3 = (unsigned)__shfl_xor((int)s3, 1);
    if (p0 > s3) ins4(s0, s1, s2, s3, p0);
    if (p1 > s3) ins4(s0, s1, s2, s3, p1);
    if (p2 > s3) ins4(s0, s1, s2, s3, p2);
    if (p3 > s3) ins4(s0, s1, s2, s3, p3);
    if (ch == 0) {
      const int grow = rb + h * 128 + row_h;
      const u32x4 outv = {s0, s1, s2, s3};
      *(u32x4*)&candq[(size_t)grow * CPR + nb * 4] = outv;
    }
  }
}

// ---------------------------------------------------------------------------
// Kernel 3: tiled transpose w [D][N] fp32 -> wT [N][D] fp32. 128x128 tiles.
// ---------------------------------------------------------------------------
__global__ __launch_bounds__(256) void k_transpose(const float* __restrict__ w,
                                                   float* __restrict__ wT) {
  __shared__ float tile[128][129];  // 66 KB
  const int t = threadIdx.x;
  const int nbase = blockIdx.x * 128;
  const int dbase = blockIdx.y * 128;
  const int c4 = (t & 31) * 4;
  const int rr = t >> 5;  // 0..7
#pragma unroll
  for (int p = 0; p < 16; p++) {
    const int d = p * 8 + rr;
    const f32x4 v = *(const f32x4*)&w[(size_t)(dbase + d) * Nn + nbase + c4];
    tile[c4 + 0][d] = v[0];
    tile[c4 + 1][d] = v[1];
    tile[c4 + 2][d] = v[2];
    tile[c4 + 3][d] = v[3];
  }
  __syncthreads();
#pragma unroll
  for (int p = 0; p < 16; p++) {
    const int n = p * 8 + rr;
    const f32x4 v = {tile[n][c4], tile[n][c4 + 1], tile[n][c4 + 2],
                     tile[n][c4 + 3]};
    *(f32x4*)&wT[(size_t)(nbase + n) * Dd + dbase + c4] = v;
  }
}

// ---------------------------------------------------------------------------
// Kernel 4: per row — stage 1 = register-resident binary-search threshold
// top-32 (no LDS staging, no serial extraction); f64 rescore; sorted top-16;
// gather. TR: coalesced wT rows.
// ---------------------------------------------------------------------------
template <bool TR>
__global__ __launch_bounds__(256) void k_final(
    const unsigned* __restrict__ candq, const float* __restrict__ label,
    const float* __restrict__ w, const float* __restrict__ wT,
    const float* __restrict__ q, float* __restrict__ out) {
  const int row = blockIdx.x;
  const int t = threadIdx.x;
  const int lane = t & 63;
  const int wv = t >> 6;

  __shared__ int sel[Mm];
  __shared__ double resc[Mm];
  __shared__ int sel16[Kk];
  __shared__ int cnt_s[4];
  __shared__ int n_gt, n_eq;
  __shared__ int eqc[64];

  // ---- stage 1: load 16 packed keys/thread, binary-search rank-32 key ----
  const unsigned* crow = candq + (size_t)row * CPR;
  unsigned kv[16];
#pragma unroll
  for (int j = 0; j < 16; j++) kv[j] = crow[t + 256 * j];

  if (t == 0) { n_gt = 0; n_eq = 0; }
  int lo = 0, hi = 65535;
  while (lo < hi) {
    const int mid = (lo + hi) >> 1;
    int c = 0;
#pragma unroll
    for (int j = 0; j < 16; j++) c += (int)((kv[j] >> 16) > (unsigned)mid);
#pragma unroll
    for (int mk = 32; mk >= 1; mk >>= 1) c += __shfl_xor(c, mk);
    if (lane == 0) cnt_s[wv] = c;
    __syncthreads();
    const int ctot = cnt_s[0] + cnt_s[1] + cnt_s[2] + cnt_s[3];
    __syncthreads();
    if (ctot < Mm) hi = mid; else lo = mid + 1;
  }
  const unsigned T = (unsigned)lo;  // key of rank-32 (count(>T) < 32 <= count(>=T))

  // emission: all key>T (set-deterministic), fill remainder from key==T by
  // smallest col (deterministic).
#pragma unroll
  for (int j = 0; j < 16; j++) {
    const unsigned k16 = kv[j] >> 16;
    if (k16 >= T) {
      const int i = t + 256 * j;
      const int col = ((i >> 2) << 7) | (int)(kv[j] & 127u);
      if (k16 > T) {
        sel[atomicAdd(&n_gt, 1)] = col;
      } else {
        const int sl2 = atomicAdd(&n_eq, 1);
        if (sl2 < 64) eqc[sl2] = col;
      }
    }
  }
  __syncthreads();
  if (t == 0) {
    const int ng = n_gt;
    const int ne = n_eq < 64 ? n_eq : 64;
    for (int r2 = ng; r2 < Mm; r2++) {
      int best = 0x7fffffff, bp2 = 0;
      for (int p2 = 0; p2 < ne; p2++)
        if (eqc[p2] < best) { best = eqc[p2]; bp2 = p2; }
      sel[r2] = best & (Nn - 1);
      eqc[bp2] = 0x7fffffff;
    }
  }
  __syncthreads();

  // ---- stage 2: per-lane f64 q-slice + per-wave redundant norm ----
  double qd[8];
#pragma unroll
  for (int j = 0; j < 8; j++) qd[j] = (double)q[row * Dd + lane * 8 + j];
  double nn = 0.0;
#pragma unroll
  for (int j = 0; j < 8; j++) nn += qd[j] * qd[j];
#pragma unroll
  for (int mk = 32; mk >= 1; mk >>= 1) nn += __shfl_xor(nn, mk);
  const double nrm = sqrt(nn);

  // ---- stage 3: wave wv rescores 8 candidates in f64 ----
#pragma unroll 1
  for (int i = 0; i < Mm / 4; i++) {
    const int c = wv * (Mm / 4) + i;
    const int idx = sel[c] & (Nn - 1);
    double d = 0.0;
    if (TR) {
      const float* wr = wT + (size_t)idx * Dd + lane * 8;
      const f32x4 wa = *(const f32x4*)wr;
      const f32x4 wb = *(const f32x4*)(wr + 4);
#pragma unroll
      for (int j = 0; j < 4; j++) d += qd[j] * (double)wa[j];
#pragma unroll
      for (int j = 0; j < 4; j++) d += qd[4 + j] * (double)wb[j];
    } else {
#pragma unroll
      for (int j = 0; j < 8; j++)
        d += qd[j] * (double)w[(size_t)(lane * 8 + j) * Nn + idx];
    }
#pragma unroll
    for (int mk = 32; mk >= 1; mk >>= 1) d += __shfl_xor(d, mk);
    if (lane == 0) resc[c] = d / nrm;
  }
  __syncthreads();

  // ---- stage 4: wave 0: sorted top-16 of 32 f64 scores ----
  float* out_sc = out + OUT_SC;
  float* out_ix = out + OUT_IDX;
  float* out_sq = out + OUT_SEQ;
  float* out_lb = out + OUT_LAB;
  if (t < 64) {
    double s = (t < Mm) ? resc[t] : -INFINITY;
    int ix = (t < Mm) ? (sel[t] & (Nn - 1)) : 0x7fffffff;
#pragma unroll 1
    for (int it = 0; it < Kk; it++) {
      double bs2 = s;
      int bi2 = ix;
      int bl = t;
#pragma unroll
      for (int mk = 32; mk >= 1; mk >>= 1) {
        const double so = __shfl_xor(bs2, mk);
        const int io = __shfl_xor(bi2, mk);
        const int lo2 = __shfl_xor(bl, mk);
        if (so > bs2 || (so == bs2 && (io < bi2 || (io == bi2 && lo2 < bl)))) {
          bs2 = so; bi2 = io; bl = lo2;
        }
      }
      if (t == 0) {
        const int safe = bi2 & (Nn - 1);
        out_sc[row * Kk + it] = (float)bs2;
        out_ix[row * Kk + it] = (float)bi2;
        out_lb[row * Kk + it] = label[safe];
        sel16[it] = safe;
      }
      if (t == bl) { s = -INFINITY; ix = 0x7fffffff; }
    }
  }
  __syncthreads();

  // ---- stage 5: gather the 16 winning weight columns ----
#pragma unroll 1
  for (int j = 0; j < Kk; j++) {
    const int idx = sel16[j];
    if (TR) {
      out_sq[(size_t)(row * Kk + j) * Dd + t] = wT[(size_t)idx * Dd + t];
      out_sq[(size_t)(row * Kk + j) * Dd + t + 256] =
          wT[(size_t)idx * Dd + t + 256];
    } else {
      out_sq[(size_t)(row * Kk + j) * Dd + t] = w[(size_t)t * Nn + idx];
      out_sq[(size_t)(row * Kk + j) * Dd + t + 256] =
          w[(size_t)(t + 256) * Nn + idx];
    }
  }
}

// ---------------------------------------------------------------------------
extern "C" void kernel_launch(void* const* d_in, const int* in_sizes, int n_in,
                              void* d_out, int out_size, void* d_ws,
                              size_t ws_size, hipStream_t stream) {
  const float* q = (const float*)d_in[0];
  const float* w = (const float*)d_in[1];
  const float* lab = (const float*)d_in[2];
  float* out = (float*)d_out;

  // workspace: qb bf16 swz (1 MB) | candq u32 (16 MB) | wT fp32 (268 MB)
  unsigned short* qb = (unsigned short*)d_ws;
  unsigned* candq = (unsigned*)((char*)d_ws + (size_t)Bq * Dd * 2);
  float* wT = (float*)((char*)candq + (size_t)Bq * CPR * 4);

  const size_t need =
      (size_t)Bq * Dd * 2 + (size_t)Bq * CPR * 4 + (size_t)Nn * Dd * 4;

  k_norm<<<Bq, 256, 0, stream>>>(q, qb);
  k_gemm<<<4096, 256, 0, stream>>>(qb, w, candq);
  if (ws_size >= need) {
    k_transpose<<<dim3(Nn / 128, Dd / 128), 256, 0, stream>>>(w, wT);
    k_final<true><<<Bq, 256, 0, stream>>>(candq, lab, w, wT, q, out);
  } else {
    k_final<false><<<Bq, 256, 0, stream>>>(candq, lab, w, wT, q, out);
  }
}

// Round 5
// 677.128 us; speedup vs baseline: 1.6376x; 1.0045x over previous
//
#include <hip/hip_runtime.h>
#include <math.h>

// Problem constants
#define Bq 1024
#define Dd 512
#define Nn 131072
#define Kk 16
#define Mm 32    // candidates rescored in f64 per row
#define CPR 4096 // candidates per row: 1024 col-blocks x top-4

// Output layout (flat concat, reference return order)
#define OUT_SC  0
#define OUT_IDX (Bq * Kk)
#define OUT_SEQ (2 * Bq * Kk)
#define OUT_LAB (2 * Bq * Kk + Bq * Kk * Dd)

using bf16x8 = __attribute__((ext_vector_type(8))) __bf16;
using f32x4  = __attribute__((ext_vector_type(4))) float;
using u16x8  = __attribute__((ext_vector_type(8))) unsigned short;
using u16x4  = __attribute__((ext_vector_type(4))) unsigned short;
using u32x4  = __attribute__((ext_vector_type(4))) unsigned;

__device__ __forceinline__ unsigned short f2bf(float f) {  // RNE f32->bf16
  unsigned u = __builtin_bit_cast(unsigned, f);
  return (unsigned short)((u + 0x7FFFu + ((u >> 16) & 1u)) >> 16);
}
__device__ __forceinline__ float bf2f(unsigned short b) {
  return __builtin_bit_cast(float, (unsigned)b << 16);
}
// monotone 16-bit key for bf16 pattern (u32 compare == float compare)
__device__ __forceinline__ unsigned key16(unsigned short b) {
  return (unsigned)(unsigned short)(b ^ ((b & 0x8000u) ? 0xFFFFu : 0x8000u));
}
// sorted-desc top-4 insertion (x = packed key<<16|col)
__device__ __forceinline__ void ins4(unsigned& s0, unsigned& s1, unsigned& s2,
                                     unsigned& s3, unsigned x) {
  unsigned mx, mn;
  mx = s0 > x ? s0 : x; mn = s0 > x ? x : s0; s0 = mx; x = mn;
  mx = s1 > x ? s1 : x; mn = s1 > x ? x : s1; s1 = mx; x = mn;
  mx = s2 > x ? s2 : x; mn = s2 > x ? x : s2; s2 = mx; x = mn;
  s3 = s3 > x ? s3 : x;
}

// async global->LDS, 16B per lane (dst must be wave-uniform base + lane*16)
#define GLD16(gp, lp)                                                   \
  __builtin_amdgcn_global_load_lds(                                     \
      (const __attribute__((address_space(1))) unsigned int*)(gp),      \
      (__attribute__((address_space(3))) unsigned int*)(lp), 16, 0, 0)

// ---------------------------------------------------------------------------
// Kernel 1: L2-normalize queries -> bf16, pre-swizzled for LDS A-tile.
// Within each 64-elem k-group, 16B chunk c stored at c ^ (row&7).
// ---------------------------------------------------------------------------
__global__ __launch_bounds__(256) void k_norm(const float* __restrict__ q,
                                              unsigned short* __restrict__ qb) {
  const int row = blockIdx.x;
  const int t = threadIdx.x;
  const float v0 = q[row * Dd + t];
  const float v1 = q[row * Dd + t + 256];
  float ss = v0 * v0 + v1 * v1;
#pragma unroll
  for (int m = 32; m >= 1; m >>= 1) ss += __shfl_xor(ss, m);
  __shared__ float wsum[4];
  if ((t & 63) == 0) wsum[t >> 6] = ss;
  __syncthreads();
  const float inv = rsqrtf(wsum[0] + wsum[1] + wsum[2] + wsum[3]);
  const int r7 = row & 7;
  const int k0 = t;
  const int p0 = (k0 & ~0x38) | ((((k0 >> 3) & 7) ^ r7) << 3);
  qb[row * Dd + p0] = f2bf(v0 * inv);
  const int k1 = t + 256;
  const int p1 = (k1 & ~0x38) | ((((k1 >> 3) & 7) ^ r7) << 3);
  qb[row * Dd + p1] = f2bf(v1 * inv);
}

// ---------------------------------------------------------------------------
// Kernel 1.5 (NEW): single-pass prep: w [D][N] fp32 ->
//   wT  [N][D] fp32 (for k_final rescore+gather, exact bits), and
//   wbT [N][D] bf16 with the qb-style XOR chunk-swizzle pre-baked
//   (so k_gemm B-staging is a pure linear global_load_lds).
// 128x128 tiles via LDS (pad 129).
// ---------------------------------------------------------------------------
__global__ __launch_bounds__(256) void k_prep(const float* __restrict__ w,
                                              float* __restrict__ wT,
                                              unsigned short* __restrict__ wbT) {
  __shared__ float tile[128][129];  // 66 KB
  const int t = threadIdx.x;
  const int nbase = blockIdx.x * 128;
  const int dbase = blockIdx.y * 128;
  const int c4 = (t & 31) * 4;
  const int rr = t >> 5;  // 0..7
#pragma unroll
  for (int p = 0; p < 16; p++) {
    const int d = p * 8 + rr;
    const f32x4 v = *(const f32x4*)&w[(size_t)(dbase + d) * Nn + nbase + c4];
    tile[c4 + 0][d] = v[0];
    tile[c4 + 1][d] = v[1];
    tile[c4 + 2][d] = v[2];
    tile[c4 + 3][d] = v[3];
  }
  __syncthreads();
#pragma unroll
  for (int p = 0; p < 16; p++) {
    const int n = p * 8 + rr;
    const f32x4 v = {tile[n][c4], tile[n][c4 + 1], tile[n][c4 + 2],
                     tile[n][c4 + 3]};
    *(f32x4*)&wT[(size_t)(nbase + n) * Dd + dbase + c4] = v;
    // bf16 swizzled: logical d-chunk cd goes to physical cd ^ (n&7)
    const int gd = dbase + c4;
    const int pos = (gd & ~0x38) | ((((gd >> 3) & 7) ^ ((nbase + n) & 7)) << 3);
    const u16x4 bv = {f2bf(v[0]), f2bf(v[1]), f2bf(v[2]), f2bf(v[3])};
    *(u16x4*)&wbT[(size_t)(nbase + n) * Dd + pos] = bv;
  }
}

// ---------------------------------------------------------------------------
// Kernel 2: bf16 MFMA GEMM + fused per-(row,128-col) top-4 selection.
// MODE 0: B staged via global_load_lds from pre-swizzled bf16 wbT (no VALU
//         conversion, no ds_write) — mirrors the A path.
// MODE 1: legacy fp32 w staging + in-register bf16 conversion (fallback).
// XCD-locality block swizzle retained (FETCH 533->144MB in R3/R4).
// ---------------------------------------------------------------------------
template <int MODE>
__global__ __launch_bounds__(256, 2) void k_gemm(
    const unsigned short* __restrict__ qb, const float* __restrict__ w,
    const unsigned short* __restrict__ wbT, unsigned* __restrict__ candq) {
  __shared__ __align__(16) unsigned char smem[256 * 64 * 2 + 128 * 72 * 2];
  unsigned short* As = (unsigned short*)smem;  // [256*64]
  unsigned short* Bs = As + 256 * 64;          // [128*64] (MODE0) / [128*72]
  const int t = threadIdx.x;
  const int l = t & 63;
  const int wv = t >> 6;
  const int m = l & 15;
  const int g = l >> 4;
  const int rowg = wv >> 1;
  const int colg = wv & 1;
  const unsigned id = blockIdx.x;
  const int bx = (int)((id >> 3) & 3);
  const int nb = (int)((id & 7) * 128 + (id >> 5));
  const int rb = bx * 256;
  const int n0 = nb * 128;
  const int ct = t & 31, dt = t >> 5;
  const int BSTRIDE = (MODE == 0) ? 64 : 72;

  f32x4 acc[8][4] = {};

  for (int kt = 0; kt < 8; kt++) {
    __syncthreads();
    // stage A: 2048 x 16B chunks via global_load_lds (qb pre-swizzled)
#pragma unroll
    for (int p = 0; p < 8; p++) {
      const int i = p * 256 + t;
      const int r = i >> 3, c = i & 7;
      GLD16(qb + (size_t)(rb + r) * Dd + kt * 64 + c * 8, &As[i * 8]);
    }
    if (MODE == 0) {
      // stage B: 1024 x 16B chunks via global_load_lds (wbT pre-swizzled)
#pragma unroll
      for (int p = 0; p < 4; p++) {
        const int i = p * 256 + t;
        const int col = i >> 3, c = i & 7;
        GLD16(wbT + (size_t)(n0 + col) * Dd + kt * 64 + c * 8, &Bs[i * 8]);
      }
    } else {
      const float* src = w + (size_t)(kt * 64 + dt * 8) * Nn + n0 + ct * 4;
#pragma unroll
      for (int h = 0; h < 2; h++) {
        f32x4 f0 = *(const f32x4*)(src + (size_t)(h * 4 + 0) * Nn);
        f32x4 f1 = *(const f32x4*)(src + (size_t)(h * 4 + 1) * Nn);
        f32x4 f2 = *(const f32x4*)(src + (size_t)(h * 4 + 2) * Nn);
        f32x4 f3 = *(const f32x4*)(src + (size_t)(h * 4 + 3) * Nn);
#pragma unroll
        for (int j = 0; j < 4; j++) {
          const int col = ct * 4 + j;
          unsigned* dst =
              (unsigned*)&Bs[col * 72 + ((dt * 8) ^ ((ct & 7) << 3))];
          dst[h * 2 + 0] =
              (unsigned)f2bf(f0[j]) | ((unsigned)f2bf(f1[j]) << 16);
          dst[h * 2 + 1] =
              (unsigned)f2bf(f2[j]) | ((unsigned)f2bf(f3[j]) << 16);
        }
      }
    }
    __syncthreads();
#pragma unroll
    for (int ks = 0; ks < 2; ks++) {
      bf16x8 b[4];
#pragma unroll
      for (int cf = 0; cf < 4; cf++) {
        const int col = colg * 64 + cf * 16 + m;
        const int kpos = (ks * 32 + g * 8) ^ ((col & 7) << 3);
        b[cf] = *(const bf16x8*)&Bs[col * BSTRIDE + kpos];
      }
#pragma unroll
      for (int rf = 0; rf < 8; rf++) {
        const int row = rowg * 128 + rf * 16 + m;
        const int cc = (ks * 4 + g) ^ (row & 7);
        const bf16x8 a = *(const bf16x8*)&As[row * 64 + cc * 8];
#pragma unroll
        for (int cf = 0; cf < 4; cf++)
          acc[rf][cf] = __builtin_amdgcn_mfma_f32_16x16x32_bf16(
              a, b[cf], acc[rf][cf], 0, 0, 0);
      }
    }
  }

  // ---- fused selection epilogue (unchanged from R4) ----
  unsigned short* tile = (unsigned short*)smem;  // [128][136] u16 keys
  const int row_h = t >> 1;
  const int ch = t & 1;
#pragma unroll 1
  for (int h = 0; h < 2; h++) {
    __syncthreads();
    if (rowg == h) {
#pragma unroll
      for (int rf = 0; rf < 8; rf++)
#pragma unroll
        for (int r = 0; r < 4; r++) {
          const int rr = rf * 16 + g * 4 + r;
#pragma unroll
          for (int cf = 0; cf < 4; cf++)
            tile[rr * 136 + colg * 64 + cf * 16 + m] =
                (unsigned short)key16(f2bf(acc[rf][cf][r]));
        }
    }
    __syncthreads();
    unsigned s0 = 0, s1 = 0, s2 = 0, s3 = 0;
    const unsigned short* trow = &tile[row_h * 136 + ch * 64];
#pragma unroll
    for (int i = 0; i < 8; i++) {
      const u16x8 tv = *(const u16x8*)&trow[i * 8];
      unsigned mx = tv[0];
#pragma unroll
      for (int j = 1; j < 8; j++) {
        const unsigned k = tv[j];
        if (k > mx) mx = k;
      }
      if (mx > (s3 >> 16)) {
#pragma unroll
        for (int j = 0; j < 8; j++) {
          const unsigned k = tv[j];
          if (k > (s3 >> 16))
            ins4(s0, s1, s2, s3,
                 (k << 16) | (unsigned)(ch * 64 + i * 8 + j));
        }
      }
    }
    const unsigned p0 = (unsigned)__shfl_xor((int)s0, 1);
    const unsigned p1 = (unsigned)__shfl_xor((int)s1, 1);
    const unsigned p2 = (unsigned)__shfl_xor((int)s2, 1);
    const unsigned p3 = (unsigned)__shfl_xor((int)s3, 1);
    if (p0 > s3) ins4(s0, s1, s2, s3, p0);
    if (p1 > s3) ins4(s0, s1, s2, s3, p1);
    if (p2 > s3) ins4(s0, s1, s2, s3, p2);
    if (p3 > s3) ins4(s0, s1, s2, s3, p3);
    if (ch == 0) {
      const int grow = rb + h * 128 + row_h;
      const u32x4 outv = {s0, s1, s2, s3};
      *(u32x4*)&candq[(size_t)grow * CPR + nb * 4] = outv;
    }
  }
}

// ---------------------------------------------------------------------------
// Kernel 3 (fallback when wbT doesn't fit): transpose-only wT fp32.
// ---------------------------------------------------------------------------
__global__ __launch_bounds__(256) void k_transpose(const float* __restrict__ w,
                                                   float* __restrict__ wT) {
  __shared__ float tile[128][129];
  const int t = threadIdx.x;
  const int nbase = blockIdx.x * 128;
  const int dbase = blockIdx.y * 128;
  const int c4 = (t & 31) * 4;
  const int rr = t >> 5;
#pragma unroll
  for (int p = 0; p < 16; p++) {
    const int d = p * 8 + rr;
    const f32x4 v = *(const f32x4*)&w[(size_t)(dbase + d) * Nn + nbase + c4];
    tile[c4 + 0][d] = v[0];
    tile[c4 + 1][d] = v[1];
    tile[c4 + 2][d] = v[2];
    tile[c4 + 3][d] = v[3];
  }
  __syncthreads();
#pragma unroll
  for (int p = 0; p < 16; p++) {
    const int n = p * 8 + rr;
    const f32x4 v = {tile[n][c4], tile[n][c4 + 1], tile[n][c4 + 2],
                     tile[n][c4 + 3]};
    *(f32x4*)&wT[(size_t)(nbase + n) * Dd + dbase + c4] = v;
  }
}

// ---------------------------------------------------------------------------
// Kernel 4 (unchanged from R4): binary-search threshold top-32; f64 rescore;
// sorted top-16; gather.
// ---------------------------------------------------------------------------
template <bool TR>
__global__ __launch_bounds__(256) void k_final(
    const unsigned* __restrict__ candq, const float* __restrict__ label,
    const float* __restrict__ w, const float* __restrict__ wT,
    const float* __restrict__ q, float* __restrict__ out) {
  const int row = blockIdx.x;
  const int t = threadIdx.x;
  const int lane = t & 63;
  const int wv = t >> 6;

  __shared__ int sel[Mm];
  __shared__ double resc[Mm];
  __shared__ int sel16[Kk];
  __shared__ int cnt_s[4];
  __shared__ int n_gt, n_eq;
  __shared__ int eqc[64];

  const unsigned* crow = candq + (size_t)row * CPR;
  unsigned kv[16];
#pragma unroll
  for (int j = 0; j < 16; j++) kv[j] = crow[t + 256 * j];

  if (t == 0) { n_gt = 0; n_eq = 0; }
  int lo = 0, hi = 65535;
  while (lo < hi) {
    const int mid = (lo + hi) >> 1;
    int c = 0;
#pragma unroll
    for (int j = 0; j < 16; j++) c += (int)((kv[j] >> 16) > (unsigned)mid);
#pragma unroll
    for (int mk = 32; mk >= 1; mk >>= 1) c += __shfl_xor(c, mk);
    if (lane == 0) cnt_s[wv] = c;
    __syncthreads();
    const int ctot = cnt_s[0] + cnt_s[1] + cnt_s[2] + cnt_s[3];
    __syncthreads();
    if (ctot < Mm) hi = mid; else lo = mid + 1;
  }
  const unsigned T = (unsigned)lo;

#pragma unroll
  for (int j = 0; j < 16; j++) {
    const unsigned k16 = kv[j] >> 16;
    if (k16 >= T) {
      const int i = t + 256 * j;
      const int col = ((i >> 2) << 7) | (int)(kv[j] & 127u);
      if (k16 > T) {
        sel[atomicAdd(&n_gt, 1)] = col;
      } else {
        const int sl2 = atomicAdd(&n_eq, 1);
        if (sl2 < 64) eqc[sl2] = col;
      }
    }
  }
  __syncthreads();
  if (t == 0) {
    const int ng = n_gt;
    const int ne = n_eq < 64 ? n_eq : 64;
    for (int r2 = ng; r2 < Mm; r2++) {
      int best = 0x7fffffff, bp2 = 0;
      for (int p2 = 0; p2 < ne; p2++)
        if (eqc[p2] < best) { best = eqc[p2]; bp2 = p2; }
      sel[r2] = best & (Nn - 1);
      eqc[bp2] = 0x7fffffff;
    }
  }
  __syncthreads();

  double qd[8];
#pragma unroll
  for (int j = 0; j < 8; j++) qd[j] = (double)q[row * Dd + lane * 8 + j];
  double nn = 0.0;
#pragma unroll
  for (int j = 0; j < 8; j++) nn += qd[j] * qd[j];
#pragma unroll
  for (int mk = 32; mk >= 1; mk >>= 1) nn += __shfl_xor(nn, mk);
  const double nrm = sqrt(nn);

#pragma unroll 1
  for (int i = 0; i < Mm / 4; i++) {
    const int c = wv * (Mm / 4) + i;
    const int idx = sel[c] & (Nn - 1);
    double d = 0.0;
    if (TR) {
      const float* wr = wT + (size_t)idx * Dd + lane * 8;
      const f32x4 wa = *(const f32x4*)wr;
      const f32x4 wb = *(const f32x4*)(wr + 4);
#pragma unroll
      for (int j = 0; j < 4; j++) d += qd[j] * (double)wa[j];
#pragma unroll
      for (int j = 0; j < 4; j++) d += qd[4 + j] * (double)wb[j];
    } else {
#pragma unroll
      for (int j = 0; j < 8; j++)
        d += qd[j] * (double)w[(size_t)(lane * 8 + j) * Nn + idx];
    }
#pragma unroll
    for (int mk = 32; mk >= 1; mk >>= 1) d += __shfl_xor(d, mk);
    if (lane == 0) resc[c] = d / nrm;
  }
  __syncthreads();

  float* out_sc = out + OUT_SC;
  float* out_ix = out + OUT_IDX;
  float* out_sq = out + OUT_SEQ;
  float* out_lb = out + OUT_LAB;
  if (t < 64) {
    double s = (t < Mm) ? resc[t] : -INFINITY;
    int ix = (t < Mm) ? (sel[t] & (Nn - 1)) : 0x7fffffff;
#pragma unroll 1
    for (int it = 0; it < Kk; it++) {
      double bs2 = s;
      int bi2 = ix;
      int bl = t;
#pragma unroll
      for (int mk = 32; mk >= 1; mk >>= 1) {
        const double so = __shfl_xor(bs2, mk);
        const int io = __shfl_xor(bi2, mk);
        const int lo2 = __shfl_xor(bl, mk);
        if (so > bs2 || (so == bs2 && (io < bi2 || (io == bi2 && lo2 < bl)))) {
          bs2 = so; bi2 = io; bl = lo2;
        }
      }
      if (t == 0) {
        const int safe = bi2 & (Nn - 1);
        out_sc[row * Kk + it] = (float)bs2;
        out_ix[row * Kk + it] = (float)bi2;
        out_lb[row * Kk + it] = label[safe];
        sel16[it] = safe;
      }
      if (t == bl) { s = -INFINITY; ix = 0x7fffffff; }
    }
  }
  __syncthreads();

#pragma unroll 1
  for (int j = 0; j < Kk; j++) {
    const int idx = sel16[j];
    if (TR) {
      out_sq[(size_t)(row * Kk + j) * Dd + t] = wT[(size_t)idx * Dd + t];
      out_sq[(size_t)(row * Kk + j) * Dd + t + 256] =
          wT[(size_t)idx * Dd + t + 256];
    } else {
      out_sq[(size_t)(row * Kk + j) * Dd + t] = w[(size_t)t * Nn + idx];
      out_sq[(size_t)(row * Kk + j) * Dd + t + 256] =
          w[(size_t)(t + 256) * Nn + idx];
    }
  }
}

// ---------------------------------------------------------------------------
extern "C" void kernel_launch(void* const* d_in, const int* in_sizes, int n_in,
                              void* d_out, int out_size, void* d_ws,
                              size_t ws_size, hipStream_t stream) {
  const float* q = (const float*)d_in[0];
  const float* w = (const float*)d_in[1];
  const float* lab = (const float*)d_in[2];
  float* out = (float*)d_out;

  // workspace: qb (1 MB) | candq (16 MB) | wT fp32 (268 MB) | wbT bf16 (134 MB)
  unsigned short* qb = (unsigned short*)d_ws;
  unsigned* candq = (unsigned*)((char*)d_ws + (size_t)Bq * Dd * 2);
  float* wT = (float*)((char*)candq + (size_t)Bq * CPR * 4);
  unsigned short* wbT = (unsigned short*)((char*)wT + (size_t)Nn * Dd * 4);

  const size_t base = (size_t)Bq * Dd * 2 + (size_t)Bq * CPR * 4;
  const size_t need_wt = base + (size_t)Nn * Dd * 4;
  const size_t need_full = need_wt + (size_t)Nn * Dd * 2;

  k_norm<<<Bq, 256, 0, stream>>>(q, qb);
  if (ws_size >= need_full) {
    k_prep<<<dim3(Nn / 128, Dd / 128), 256, 0, stream>>>(w, wT, wbT);
    k_gemm<0><<<4096, 256, 0, stream>>>(qb, w, wbT, candq);
    k_final<true><<<Bq, 256, 0, stream>>>(candq, lab, w, wT, q, out);
  } else if (ws_size >= need_wt) {
    k_gemm<1><<<4096, 256, 0, stream>>>(qb, w, wbT, candq);
    k_transpose<<<dim3(Nn / 128, Dd / 128), 256, 0, stream>>>(w, wT);
    k_final<true><<<Bq, 256, 0, stream>>>(candq, lab, w, wT, q, out);
  } else {
    k_gemm<1><<<4096, 256, 0, stream>>>(qb, w, wbT, candq);
    k_final<false><<<Bq, 256, 0, stream>>>(candq, lab, w, wT, q, out);
  }
}